// Round 3
// baseline (734.895 us; speedup 1.0000x reference)
//
#include <hip/hip_runtime.h>
#include <math.h>

#define NTOK 131072
#define KC   1024
#define DIMV 64

#define OUT_LOSS 0
#define OUT_Q    1
#define OUT_PERP (1 + NTOK * DIMV)
#define OUT_IDX  (2 + NTOK * DIMV)

#define MARGIN 1.5e-4f   // > 3x worst-case comparison error bound (4.3e-5)
#define XROW   72        // LDS row pitch in shorts: 64 + 8 pad (breaks 16-way bank conflict)

typedef __attribute__((ext_vector_type(8))) short short8;
typedef __attribute__((ext_vector_type(4))) float f32x4;

// numpy pairwise_sum mimic for n=64 of v[i]*v[i] (bit-exact vs np reference,
// verified rounds 1-2: overall absmax 0.0).
__device__ __forceinline__ float sumsq64_np(const float v[DIMV]) {
#pragma clang fp contract(off)
  {
    float r[8];
#pragma unroll
    for (int j = 0; j < 8; ++j) r[j] = v[j] * v[j];
#pragma unroll
    for (int i = 8; i < 64; i += 8) {
#pragma unroll
      for (int j = 0; j < 8; ++j) r[j] += v[i + j] * v[i + j];
    }
    return ((r[0] + r[1]) + (r[2] + r[3])) + ((r[4] + r[5]) + (r[6] + r[7]));
  }
}

// RNE bf16 hi/lo split: f ~= hi + lo, |residual| <= 2^-18 |f|
__device__ __forceinline__ void bsplit(float f, unsigned short& h, unsigned short& l) {
  unsigned int u = __float_as_uint(f);
  unsigned int r = u + 0x7fffu + ((u >> 16) & 1u);
  unsigned short hb = (unsigned short)(r >> 16);
  float fh = __uint_as_float((unsigned int)hb << 16);
  float lo = f - fh;                       // exact (Sterbenz)
  unsigned int u2 = __float_as_uint(lo);
  unsigned int r2 = u2 + 0x7fffu + ((u2 >> 16) & 1u);
  h = hb;
  l = (unsigned short)(r2 >> 16);
}

// ---------------- prep: split codebook to bf16 hi/lo + exact |e|^2 ----------
__global__ void __launch_bounds__(256)
vq_prep_kernel(const float* __restrict__ cb, unsigned short* __restrict__ cbh,
               unsigned short* __restrict__ cbl, float* __restrict__ ee) {
  const int k = blockIdx.x * 256 + threadIdx.x;   // grid 4*256 = 1024 exact
  float e[DIMV];
  const float4* e4 = reinterpret_cast<const float4*>(cb + k * DIMV);
#pragma unroll
  for (int i = 0; i < 16; ++i) {
    float4 t = e4[i];
    e[4 * i + 0] = t.x; e[4 * i + 1] = t.y;
    e[4 * i + 2] = t.z; e[4 * i + 3] = t.w;
  }
  ee[k] = sumsq64_np(e);
#pragma unroll
  for (int i = 0; i < DIMV; ++i) {
    unsigned short h, l;
    bsplit(e[i], h, l);
    cbh[k * DIMV + i] = h;
    cbl[k * DIMV + i] = l;
  }
}

// ---------------- phase A: MFMA approx scores + min1/min2 + margin flag -----
__device__ __forceinline__ void upd(float& m1, float& m2, int& i1, float s, int c) {
  bool lt = s < m1;
  m2 = lt ? m1 : fminf(m2, s);
  i1 = lt ? c : i1;
  m1 = lt ? s : m1;
}

__global__ void __launch_bounds__(256, 2)
vq_mfma_kernel(const float* __restrict__ xin, const unsigned short* __restrict__ cbh,
               const unsigned short* __restrict__ cbl, const float* __restrict__ ee,
               float* __restrict__ out) {
  __shared__ unsigned short sXh[64 * XROW];   // 9216 B
  __shared__ unsigned short sXl[64 * XROW];
  __shared__ unsigned short sEh[128 * XROW];  // 18432 B
  __shared__ unsigned short sEl[128 * XROW];
  __shared__ float sEe[128];

  const int tid = threadIdx.x;
  const int tokenBase = blockIdx.x * 64;

  // Stage + split X: 64 tokens x 64 dims -> LDS bf16 hi/lo (padded rows).
  for (int fg = tid; fg < 512; fg += 256) {
    int tok = fg >> 3, piece = fg & 7;
    const float4* src =
        reinterpret_cast<const float4*>(xin + (tokenBase + tok) * DIMV + piece * 8);
    float4 u = src[0], v = src[1];
    float xs[8] = {u.x, u.y, u.z, u.w, v.x, v.y, v.z, v.w};
    short8 hh, ll;
#pragma unroll
    for (int i = 0; i < 8; ++i) {
      unsigned short h, l;
      bsplit(xs[i], h, l);
      hh[i] = (short)h; ll[i] = (short)l;
    }
    *(short8*)&sXh[tok * XROW + piece * 8] = hh;
    *(short8*)&sXl[tok * XROW + piece * 8] = ll;
  }
  __syncthreads();

  const int lane = tid & 63, wave = tid >> 6;
  const int q = lane >> 4, n16 = lane & 15;
  const int arow = wave * 16 + n16;   // A-operand row = token_local

  // A fragments, constant for whole kernel. A[m=lane&15][k=q*8+j], K-half h -> +32.
  short8 axh0 = *(const short8*)&sXh[arow * XROW + 0 + q * 8];
  short8 axh1 = *(const short8*)&sXh[arow * XROW + 32 + q * 8];
  short8 axl0 = *(const short8*)&sXl[arow * XROW + 0 + q * 8];
  short8 axl1 = *(const short8*)&sXl[arow * XROW + 32 + q * 8];

  float min1[4], min2[4];
  int idx1[4];
#pragma unroll
  for (int r = 0; r < 4; ++r) { min1[r] = 1e30f; min2[r] = 1e30f; idx1[r] = 0; }

#pragma unroll 1
  for (int ch = 0; ch < 8; ++ch) {
    __syncthreads();
    const int cbase = ch * 128;
    for (int fg = tid; fg < 1024; fg += 256) {   // 128 rows x 8 pieces
      int row = fg >> 3, piece = fg & 7;
      *(short8*)&sEh[row * XROW + piece * 8] =
          *(const short8*)&cbh[(cbase + row) * DIMV + piece * 8];
      *(short8*)&sEl[row * XROW + piece * 8] =
          *(const short8*)&cbl[(cbase + row) * DIMV + piece * 8];
    }
    if (tid < 128) sEe[tid] = ee[cbase + tid];
    __syncthreads();

#pragma unroll 1
    for (int t = 0; t < 8; t += 2) {   // 2-tile ILP (2 independent MFMA chains)
      const int c0 = (t + 0) * 16 + n16;   // B row = code_local (n = lane&15)
      const int c1 = (t + 1) * 16 + n16;
      short8 b0h0 = *(const short8*)&sEh[c0 * XROW + 0 + q * 8];
      short8 b0h1 = *(const short8*)&sEh[c0 * XROW + 32 + q * 8];
      short8 b0l0 = *(const short8*)&sEl[c0 * XROW + 0 + q * 8];
      short8 b0l1 = *(const short8*)&sEl[c0 * XROW + 32 + q * 8];
      short8 b1h0 = *(const short8*)&sEh[c1 * XROW + 0 + q * 8];
      short8 b1h1 = *(const short8*)&sEh[c1 * XROW + 32 + q * 8];
      short8 b1l0 = *(const short8*)&sEl[c1 * XROW + 0 + q * 8];
      short8 b1l1 = *(const short8*)&sEl[c1 * XROW + 32 + q * 8];
      f32x4 acc0 = {0.0f, 0.0f, 0.0f, 0.0f};
      f32x4 acc1 = {0.0f, 0.0f, 0.0f, 0.0f};
      acc0 = __builtin_amdgcn_mfma_f32_16x16x32_bf16(axh0, b0h0, acc0, 0, 0, 0);
      acc1 = __builtin_amdgcn_mfma_f32_16x16x32_bf16(axh0, b1h0, acc1, 0, 0, 0);
      acc0 = __builtin_amdgcn_mfma_f32_16x16x32_bf16(axh1, b0h1, acc0, 0, 0, 0);
      acc1 = __builtin_amdgcn_mfma_f32_16x16x32_bf16(axh1, b1h1, acc1, 0, 0, 0);
      acc0 = __builtin_amdgcn_mfma_f32_16x16x32_bf16(axh0, b0l0, acc0, 0, 0, 0);
      acc1 = __builtin_amdgcn_mfma_f32_16x16x32_bf16(axh0, b1l0, acc1, 0, 0, 0);
      acc0 = __builtin_amdgcn_mfma_f32_16x16x32_bf16(axh1, b0l1, acc0, 0, 0, 0);
      acc1 = __builtin_amdgcn_mfma_f32_16x16x32_bf16(axh1, b1l1, acc1, 0, 0, 0);
      acc0 = __builtin_amdgcn_mfma_f32_16x16x32_bf16(axl0, b0h0, acc0, 0, 0, 0);
      acc1 = __builtin_amdgcn_mfma_f32_16x16x32_bf16(axl0, b1h0, acc1, 0, 0, 0);
      acc0 = __builtin_amdgcn_mfma_f32_16x16x32_bf16(axl1, b0h1, acc0, 0, 0, 0);
      acc1 = __builtin_amdgcn_mfma_f32_16x16x32_bf16(axl1, b1h1, acc1, 0, 0, 0);

      float e0 = sEe[(t + 0) * 16 + n16];
      float e1 = sEe[(t + 1) * 16 + n16];
      const int g0 = cbase + (t + 0) * 16 + n16;
      const int g1 = cbase + (t + 1) * 16 + n16;
#pragma unroll
      for (int r = 0; r < 4; ++r) {
        float s0 = __builtin_fmaf(-2.0f, acc0[r], e0);
        upd(min1[r], min2[r], idx1[r], s0, g0);
        float s1 = __builtin_fmaf(-2.0f, acc1[r], e1);
        upd(min1[r], min2[r], idx1[r], s1, g1);
      }
    }
  }

  // Cross-lane merge over the 16 lanes sharing tokens (same q, lane&15 = 0..15).
  // C/D layout: col=lane&15, row=q*4+r -> lane's 4 trackers are tokens q*4+r.
#pragma unroll
  for (int r = 0; r < 4; ++r) {
    float m1 = min1[r], m2 = min2[r];
    int i1 = idx1[r];
#pragma unroll
    for (int m = 1; m < 16; m <<= 1) {
      float om1 = __shfl_xor(m1, m, 64);
      float om2 = __shfl_xor(m2, m, 64);
      int   oi1 = __shfl_xor(i1, m, 64);
      bool lt = om1 < m1;   // tie -> keep ours; flag logic makes order irrelevant
      float nm2 = lt ? fminf(om2, m1) : fminf(m2, om1);
      m1 = lt ? om1 : m1;
      i1 = lt ? oi1 : i1;
      m2 = nm2;
    }
    if (n16 == 0) {
      int tok = tokenBase + wave * 16 + q * 4 + r;
      bool flagged = (m2 <= m1 + MARGIN);
      out[OUT_IDX + tok] = flagged ? -1.0f : (float)i1;
    }
  }
}

// ---------------- phase B: exact rescan (reference arithmetic) for flagged --
__global__ void __launch_bounds__(256)
vq_exact_kernel(const float* __restrict__ xin, const float* __restrict__ cb,
                const float* __restrict__ ee, float* __restrict__ out) {
  const int lane = threadIdx.x & 63;
  const int gwave = (blockIdx.x * 256 + threadIdx.x) >> 6;   // 1024 waves

#pragma unroll 1
  for (int t = gwave; t < NTOK; t += 1024) {
    float f = out[OUT_IDX + t];
    if (f >= 0.0f) continue;   // wave-uniform

    float x[DIMV];
    const float4* x4 = reinterpret_cast<const float4*>(xin + (long)t * DIMV);
#pragma unroll
    for (int i = 0; i < 16; ++i) {
      float4 u = x4[i];
      x[4 * i + 0] = u.x; x[4 * i + 1] = u.y;
      x[4 * i + 2] = u.z; x[4 * i + 3] = u.w;
    }
    float xx = sumsq64_np(x);

    float bd = 1e30f;
    int bi = 0x7fffffff;
#pragma unroll 1
    for (int kk = 0; kk < 16; kk += 2) {   // 2-code ILP per lane
      const int c0 = (kk + 0) * 64 + lane;
      const int c1 = (kk + 1) * 64 + lane;
      const float4* e0 = reinterpret_cast<const float4*>(cb + (long)c0 * DIMV);
      const float4* e1 = reinterpret_cast<const float4*>(cb + (long)c1 * DIMV);
      float d0 = 0.0f, d1 = 0.0f;
#pragma unroll 4
      for (int i = 0; i < 16; ++i) {     // sequential fma, ascending dims: exact
        float4 a = e0[i];
        float4 b = e1[i];
        d0 = __builtin_fmaf(a.x, x[4 * i + 0], d0);
        d1 = __builtin_fmaf(b.x, x[4 * i + 0], d1);
        d0 = __builtin_fmaf(a.y, x[4 * i + 1], d0);
        d1 = __builtin_fmaf(b.y, x[4 * i + 1], d1);
        d0 = __builtin_fmaf(a.z, x[4 * i + 2], d0);
        d1 = __builtin_fmaf(b.z, x[4 * i + 2], d1);
        d0 = __builtin_fmaf(a.w, x[4 * i + 3], d0);
        d1 = __builtin_fmaf(b.w, x[4 * i + 3], d1);
      }
      float dd0 = (xx - 2.0f * d0) + ee[c0];   // exact reference expression
      float dd1 = (xx - 2.0f * d1) + ee[c1];
      bool t0 = (dd0 < bd) || (dd0 == bd && c0 < bi);
      bd = t0 ? dd0 : bd; bi = t0 ? c0 : bi;
      bool t1 = (dd1 < bd) || (dd1 == bd && c1 < bi);
      bd = t1 ? dd1 : bd; bi = t1 ? c1 : bi;
    }
    // wave lex-min (first-occurrence argmin)
#pragma unroll
    for (int m = 1; m < 64; m <<= 1) {
      float od = __shfl_xor(bd, m, 64);
      int   oi = __shfl_xor(bi, m, 64);
      bool take = (od < bd) || (od == bd && oi < bi);
      bd = take ? od : bd;
      bi = take ? oi : bi;
    }
    if (lane == 0) out[OUT_IDX + t] = (float)bi;
  }
}

// ---------------- epilogue: gather/quantize/mse/hist (round-2 proven) -------
__global__ void __launch_bounds__(256)
vq_epilogue_kernel(const float* __restrict__ xin, const float* __restrict__ cb,
                   float* __restrict__ out, float* __restrict__ ws_mse,
                   unsigned int* __restrict__ ws_hist) {
  __shared__ unsigned int s_hist[KC];
  __shared__ float s_red[256];
  __shared__ int s_bidx[256];
  const int tid = threadIdx.x;
  for (int k = tid; k < KC; k += 256) s_hist[k] = 0u;
  __syncthreads();

  const int token = blockIdx.x * 256 + tid;
  const int bidx = (int)out[OUT_IDX + token];
  s_bidx[tid] = bidx;
  atomicAdd(&s_hist[bidx], 1u);
  __syncthreads();

  const float* xblk = xin + (size_t)blockIdx.x * (256 * DIMV);
  float* oq = out + OUT_Q + (size_t)blockIdx.x * (256 * DIMV);
  float acc = 0.0f;
#pragma unroll 4
  for (int j = 0; j < 64; ++j) {
    int g = tid + 256 * j;
    int tl = g >> 6;
    int dim = g & 63;
    float xv = xblk[g];
    float ev = cb[(long)s_bidx[tl] * DIMV + dim];
    float dmx = ev - xv;
    float qst = xv + dmx;
    acc = __builtin_fmaf(dmx, dmx, acc);
    oq[g] = qst;
  }

  s_red[tid] = acc;
  __syncthreads();
#pragma unroll
  for (int s = 128; s > 0; s >>= 1) {
    if (tid < s) s_red[tid] += s_red[tid + s];
    __syncthreads();
  }
  if (tid == 0) atomicAdd(ws_mse, s_red[0]);

  for (int k = tid; k < KC; k += 256) {
    unsigned int c = s_hist[k];
    if (c) atomicAdd(&ws_hist[k], c);
  }
}

__global__ void __launch_bounds__(1024)
vq_final_kernel(const unsigned int* __restrict__ ws_hist,
                const float* __restrict__ ws_mse, float* __restrict__ out) {
  __shared__ float s_red[1024];
  const int t = threadIdx.x;
  float p = (float)ws_hist[t] / 131072.0f;
  float term = p * logf(p + 1e-10f);
  s_red[t] = term;
  __syncthreads();
#pragma unroll
  for (int s = 512; s > 0; s >>= 1) {
    if (t < s) s_red[t] += s_red[t + s];
    __syncthreads();
  }
  if (t == 0) {
    out[OUT_PERP] = expf(-s_red[0]);
    float mse = ws_mse[0] / 8388608.0f;
    out[OUT_LOSS] = mse + 0.25f * mse;
  }
}

extern "C" void kernel_launch(void* const* d_in, const int* in_sizes, int n_in,
                              void* d_out, int out_size, void* d_ws, size_t ws_size,
                              hipStream_t stream) {
  (void)in_sizes; (void)n_in; (void)out_size; (void)ws_size;
  const float* xin = (const float*)d_in[0];
  const float* cb  = (const float*)d_in[1];
  float* out = (float*)d_out;

  char* wsb = (char*)d_ws;
  float* ws_mse = (float*)wsb;                              // [0,4)
  unsigned int* ws_hist = (unsigned int*)(wsb + 4);         // [4,4100)
  float* ws_ee = (float*)(wsb + 4352);                      // [4352,8448)
  unsigned short* ws_cbh = (unsigned short*)(wsb + 8448);   // [8448,139520)
  unsigned short* ws_cbl = (unsigned short*)(wsb + 139520); // [139520,270592)

  hipMemsetAsync(d_ws, 0, 4100, stream);
  hipLaunchKernelGGL(vq_prep_kernel, dim3(4), dim3(256), 0, stream,
                     cb, ws_cbh, ws_cbl, ws_ee);
  hipLaunchKernelGGL(vq_mfma_kernel, dim3(NTOK / 64), dim3(256), 0, stream,
                     xin, ws_cbh, ws_cbl, ws_ee, out);
  hipLaunchKernelGGL(vq_exact_kernel, dim3(256), dim3(256), 0, stream,
                     xin, cb, ws_ee, out);
  hipLaunchKernelGGL(vq_epilogue_kernel, dim3(NTOK / 256), dim3(256), 0, stream,
                     xin, cb, out, ws_mse, ws_hist);
  hipLaunchKernelGGL(vq_final_kernel, dim3(1), dim3(1024), 0, stream,
                     ws_hist, ws_mse, out);
}

// Round 4
// 553.737 us; speedup vs baseline: 1.3272x; 1.3272x over previous
//
#include <hip/hip_runtime.h>
#include <math.h>

#define NTOK 131072
#define KC   1024
#define DIMV 64

#define OUT_LOSS 0
#define OUT_Q    1
#define OUT_PERP (1 + NTOK * DIMV)
#define OUT_IDX  (2 + NTOK * DIMV)

#define MARGIN 1.5e-4f   // > 3x worst-case comparison error bound
#define XROW   72        // LDS row pitch in shorts: 64 + 8 pad

typedef __attribute__((ext_vector_type(8))) short short8;
typedef __attribute__((ext_vector_type(4))) float f32x4;

// numpy pairwise_sum mimic for n=64 of v[i]*v[i] (bit-exact vs np reference,
// verified rounds 1-3: overall absmax 0.0).
__device__ __forceinline__ float sumsq64_np(const float v[DIMV]) {
#pragma clang fp contract(off)
  {
    float r[8];
#pragma unroll
    for (int j = 0; j < 8; ++j) r[j] = v[j] * v[j];
#pragma unroll
    for (int i = 8; i < 64; i += 8) {
#pragma unroll
      for (int j = 0; j < 8; ++j) r[j] += v[i + j] * v[i + j];
    }
    return ((r[0] + r[1]) + (r[2] + r[3])) + ((r[4] + r[5]) + (r[6] + r[7]));
  }
}

// RNE bf16 hi/lo split: f ~= hi + lo, |residual| <= 2^-18 |f|
__device__ __forceinline__ void bsplit(float f, unsigned short& h, unsigned short& l) {
  unsigned int u = __float_as_uint(f);
  unsigned int r = u + 0x7fffu + ((u >> 16) & 1u);
  unsigned short hb = (unsigned short)(r >> 16);
  float fh = __uint_as_float((unsigned int)hb << 16);
  float lo = f - fh;                       // exact (Sterbenz)
  unsigned int u2 = __float_as_uint(lo);
  unsigned int r2 = u2 + 0x7fffu + ((u2 >> 16) & 1u);
  h = hb;
  l = (unsigned short)(r2 >> 16);
}

// ---------------- prep: split codebook to bf16 hi/lo + exact |e|^2 ----------
__global__ void __launch_bounds__(256)
vq_prep_kernel(const float* __restrict__ cb, unsigned short* __restrict__ cbh,
               unsigned short* __restrict__ cbl, float* __restrict__ ee) {
  const int k = blockIdx.x * 256 + threadIdx.x;   // grid 4*256 = 1024 exact
  float e[DIMV];
  const float4* e4 = reinterpret_cast<const float4*>(cb + k * DIMV);
#pragma unroll
  for (int i = 0; i < 16; ++i) {
    float4 t = e4[i];
    e[4 * i + 0] = t.x; e[4 * i + 1] = t.y;
    e[4 * i + 2] = t.z; e[4 * i + 3] = t.w;
  }
  ee[k] = sumsq64_np(e);
#pragma unroll
  for (int i = 0; i < DIMV; ++i) {
    unsigned short h, l;
    bsplit(e[i], h, l);
    cbh[k * DIMV + i] = h;
    cbl[k * DIMV + i] = l;
  }
}

// ---------------- phase A: MFMA approx scores + min1/min2 + margin flag -----
__device__ __forceinline__ void upd(float& m1, float& m2, int& i1, float s, int c) {
  bool lt = s < m1;
  m2 = lt ? m1 : fminf(m2, s);
  i1 = lt ? c : i1;
  m1 = lt ? s : m1;
}

__global__ void __launch_bounds__(256, 2)
vq_mfma_kernel(const float* __restrict__ xin, const unsigned short* __restrict__ cbh,
               const unsigned short* __restrict__ cbl, const float* __restrict__ ee,
               float* __restrict__ out) {
  __shared__ unsigned short sXh[64 * XROW];
  __shared__ unsigned short sXl[64 * XROW];
  __shared__ unsigned short sEh[128 * XROW];
  __shared__ unsigned short sEl[128 * XROW];
  __shared__ float sEe[128];

  const int tid = threadIdx.x;
  const int tokenBase = blockIdx.x * 64;

  for (int fg = tid; fg < 512; fg += 256) {
    int tok = fg >> 3, piece = fg & 7;
    const float4* src =
        reinterpret_cast<const float4*>(xin + (tokenBase + tok) * DIMV + piece * 8);
    float4 u = src[0], v = src[1];
    float xs[8] = {u.x, u.y, u.z, u.w, v.x, v.y, v.z, v.w};
    short8 hh, ll;
#pragma unroll
    for (int i = 0; i < 8; ++i) {
      unsigned short h, l;
      bsplit(xs[i], h, l);
      hh[i] = (short)h; ll[i] = (short)l;
    }
    *(short8*)&sXh[tok * XROW + piece * 8] = hh;
    *(short8*)&sXl[tok * XROW + piece * 8] = ll;
  }
  __syncthreads();

  const int lane = tid & 63, wave = tid >> 6;
  const int q = lane >> 4, n16 = lane & 15;
  const int arow = wave * 16 + n16;

  short8 axh0 = *(const short8*)&sXh[arow * XROW + 0 + q * 8];
  short8 axh1 = *(const short8*)&sXh[arow * XROW + 32 + q * 8];
  short8 axl0 = *(const short8*)&sXl[arow * XROW + 0 + q * 8];
  short8 axl1 = *(const short8*)&sXl[arow * XROW + 32 + q * 8];

  float min1[4], min2[4];
  int idx1[4];
#pragma unroll
  for (int r = 0; r < 4; ++r) { min1[r] = 1e30f; min2[r] = 1e30f; idx1[r] = 0; }

#pragma unroll 1
  for (int ch = 0; ch < 8; ++ch) {
    __syncthreads();
    const int cbase = ch * 128;
    for (int fg = tid; fg < 1024; fg += 256) {
      int row = fg >> 3, piece = fg & 7;
      *(short8*)&sEh[row * XROW + piece * 8] =
          *(const short8*)&cbh[(cbase + row) * DIMV + piece * 8];
      *(short8*)&sEl[row * XROW + piece * 8] =
          *(const short8*)&cbl[(cbase + row) * DIMV + piece * 8];
    }
    if (tid < 128) sEe[tid] = ee[cbase + tid];
    __syncthreads();

#pragma unroll 1
    for (int t = 0; t < 8; t += 2) {
      const int c0 = (t + 0) * 16 + n16;
      const int c1 = (t + 1) * 16 + n16;
      short8 b0h0 = *(const short8*)&sEh[c0 * XROW + 0 + q * 8];
      short8 b0h1 = *(const short8*)&sEh[c0 * XROW + 32 + q * 8];
      short8 b0l0 = *(const short8*)&sEl[c0 * XROW + 0 + q * 8];
      short8 b0l1 = *(const short8*)&sEl[c0 * XROW + 32 + q * 8];
      short8 b1h0 = *(const short8*)&sEh[c1 * XROW + 0 + q * 8];
      short8 b1h1 = *(const short8*)&sEh[c1 * XROW + 32 + q * 8];
      short8 b1l0 = *(const short8*)&sEl[c1 * XROW + 0 + q * 8];
      short8 b1l1 = *(const short8*)&sEl[c1 * XROW + 32 + q * 8];
      f32x4 acc0 = {0.0f, 0.0f, 0.0f, 0.0f};
      f32x4 acc1 = {0.0f, 0.0f, 0.0f, 0.0f};
      acc0 = __builtin_amdgcn_mfma_f32_16x16x32_bf16(axh0, b0h0, acc0, 0, 0, 0);
      acc1 = __builtin_amdgcn_mfma_f32_16x16x32_bf16(axh0, b1h0, acc1, 0, 0, 0);
      acc0 = __builtin_amdgcn_mfma_f32_16x16x32_bf16(axh1, b0h1, acc0, 0, 0, 0);
      acc1 = __builtin_amdgcn_mfma_f32_16x16x32_bf16(axh1, b1h1, acc1, 0, 0, 0);
      acc0 = __builtin_amdgcn_mfma_f32_16x16x32_bf16(axh0, b0l0, acc0, 0, 0, 0);
      acc1 = __builtin_amdgcn_mfma_f32_16x16x32_bf16(axh0, b1l0, acc1, 0, 0, 0);
      acc0 = __builtin_amdgcn_mfma_f32_16x16x32_bf16(axh1, b0l1, acc0, 0, 0, 0);
      acc1 = __builtin_amdgcn_mfma_f32_16x16x32_bf16(axh1, b1l1, acc1, 0, 0, 0);
      acc0 = __builtin_amdgcn_mfma_f32_16x16x32_bf16(axl0, b0h0, acc0, 0, 0, 0);
      acc1 = __builtin_amdgcn_mfma_f32_16x16x32_bf16(axl0, b1h0, acc1, 0, 0, 0);
      acc0 = __builtin_amdgcn_mfma_f32_16x16x32_bf16(axl1, b0h1, acc0, 0, 0, 0);
      acc1 = __builtin_amdgcn_mfma_f32_16x16x32_bf16(axl1, b1h1, acc1, 0, 0, 0);

      float e0 = sEe[(t + 0) * 16 + n16];
      float e1 = sEe[(t + 1) * 16 + n16];
      const int g0 = cbase + (t + 0) * 16 + n16;
      const int g1 = cbase + (t + 1) * 16 + n16;
#pragma unroll
      for (int r = 0; r < 4; ++r) {
        float s0 = __builtin_fmaf(-2.0f, acc0[r], e0);
        upd(min1[r], min2[r], idx1[r], s0, g0);
        float s1 = __builtin_fmaf(-2.0f, acc1[r], e1);
        upd(min1[r], min2[r], idx1[r], s1, g1);
      }
    }
  }

#pragma unroll
  for (int r = 0; r < 4; ++r) {
    float m1 = min1[r], m2 = min2[r];
    int i1 = idx1[r];
#pragma unroll
    for (int m = 1; m < 16; m <<= 1) {
      float om1 = __shfl_xor(m1, m, 64);
      float om2 = __shfl_xor(m2, m, 64);
      int   oi1 = __shfl_xor(i1, m, 64);
      bool lt = om1 < m1;
      float nm2 = lt ? fminf(om2, m1) : fminf(m2, om1);
      m1 = lt ? om1 : m1;
      i1 = lt ? oi1 : i1;
      m2 = nm2;
    }
    if (n16 == 0) {
      int tok = tokenBase + wave * 16 + q * 4 + r;
      bool flagged = (m2 <= m1 + MARGIN);
      out[OUT_IDX + tok] = flagged ? -1.0f : (float)i1;
    }
  }
}

// ---------------- phase B: exact rescan (reference arithmetic) for flagged --
// Ballot scan: 1024 waves x 2 iters; 64 flags loaded coalesced per wave-iter,
// flagged tokens processed cooperatively by the whole wave. i-loop FULLY
// unrolled -> x[] constant-indexed -> stays in VGPRs (round-3 spill fix).
__global__ void __launch_bounds__(256)
vq_exact_kernel(const float* __restrict__ xin, const float* __restrict__ cb,
                const float* __restrict__ ee, float* __restrict__ out) {
  const int lane = threadIdx.x & 63;
  const int gwave = (blockIdx.x * 256 + threadIdx.x) >> 6;   // [0,1024)

#pragma unroll 1
  for (int it = 0; it < 2; ++it) {
    const int base = (gwave * 2 + it) * 64;
    float f = out[OUT_IDX + base + lane];      // coalesced
    unsigned long long mask = __ballot(f < 0.0f);

    while (mask) {
      const int b = __ffsll((long long)mask) - 1;
      mask &= mask - 1;
      const int t = base + b;                  // wave-uniform

      float x[DIMV];
      const float4* x4 = reinterpret_cast<const float4*>(xin + (long)t * DIMV);
#pragma unroll
      for (int i = 0; i < 16; ++i) {
        float4 u = x4[i];
        x[4 * i + 0] = u.x; x[4 * i + 1] = u.y;
        x[4 * i + 2] = u.z; x[4 * i + 3] = u.w;
      }
      float xx = sumsq64_np(x);

      float bd = 1e30f;
      int bi = 0x7fffffff;
#pragma unroll 1
      for (int kk = 0; kk < 16; ++kk) {        // 1 code/lane/iter: no hoist blowup
        const int c = kk * 64 + lane;
        const float4* e4 = reinterpret_cast<const float4*>(cb + (long)c * DIMV);
        float d = 0.0f;
#pragma unroll
        for (int i = 0; i < 16; ++i) {         // FULL unroll: constant x indices
          float4 a = e4[i];
          d = __builtin_fmaf(a.x, x[4 * i + 0], d);
          d = __builtin_fmaf(a.y, x[4 * i + 1], d);
          d = __builtin_fmaf(a.z, x[4 * i + 2], d);
          d = __builtin_fmaf(a.w, x[4 * i + 3], d);
        }
        float dd = (xx - 2.0f * d) + ee[c];    // exact reference expression
        bool tk = (dd < bd) || (dd == bd && c < bi);
        bd = tk ? dd : bd;
        bi = tk ? c : bi;
      }
      // wave lex-min (first-occurrence argmin)
#pragma unroll
      for (int m = 1; m < 64; m <<= 1) {
        float od = __shfl_xor(bd, m, 64);
        int   oi = __shfl_xor(bi, m, 64);
        bool take = (od < bd) || (od == bd && oi < bi);
        bd = take ? od : bd;
        bi = take ? oi : bi;
      }
      if (lane == 0) out[OUT_IDX + t] = (float)bi;
    }
  }
}

// ---------------- epilogue: gather/quantize/mse/hist (round-2 proven) -------
__global__ void __launch_bounds__(256)
vq_epilogue_kernel(const float* __restrict__ xin, const float* __restrict__ cb,
                   float* __restrict__ out, float* __restrict__ ws_mse,
                   unsigned int* __restrict__ ws_hist) {
  __shared__ unsigned int s_hist[KC];
  __shared__ float s_red[256];
  __shared__ int s_bidx[256];
  const int tid = threadIdx.x;
  for (int k = tid; k < KC; k += 256) s_hist[k] = 0u;
  __syncthreads();

  const int token = blockIdx.x * 256 + tid;
  const int bidx = (int)out[OUT_IDX + token];
  s_bidx[tid] = bidx;
  atomicAdd(&s_hist[bidx], 1u);
  __syncthreads();

  const float* xblk = xin + (size_t)blockIdx.x * (256 * DIMV);
  float* oq = out + OUT_Q + (size_t)blockIdx.x * (256 * DIMV);
  float acc = 0.0f;
#pragma unroll 4
  for (int j = 0; j < 64; ++j) {
    int g = tid + 256 * j;
    int tl = g >> 6;
    int dim = g & 63;
    float xv = xblk[g];
    float ev = cb[(long)s_bidx[tl] * DIMV + dim];
    float dmx = ev - xv;
    float qst = xv + dmx;
    acc = __builtin_fmaf(dmx, dmx, acc);
    oq[g] = qst;
  }

  s_red[tid] = acc;
  __syncthreads();
#pragma unroll
  for (int s = 128; s > 0; s >>= 1) {
    if (tid < s) s_red[tid] += s_red[tid + s];
    __syncthreads();
  }
  if (tid == 0) atomicAdd(ws_mse, s_red[0]);

  for (int k = tid; k < KC; k += 256) {
    unsigned int c = s_hist[k];
    if (c) atomicAdd(&ws_hist[k], c);
  }
}

__global__ void __launch_bounds__(1024)
vq_final_kernel(const unsigned int* __restrict__ ws_hist,
                const float* __restrict__ ws_mse, float* __restrict__ out) {
  __shared__ float s_red[1024];
  const int t = threadIdx.x;
  float p = (float)ws_hist[t] / 131072.0f;
  float term = p * logf(p + 1e-10f);
  s_red[t] = term;
  __syncthreads();
#pragma unroll
  for (int s = 512; s > 0; s >>= 1) {
    if (t < s) s_red[t] += s_red[t + s];
    __syncthreads();
  }
  if (t == 0) {
    out[OUT_PERP] = expf(-s_red[0]);
    float mse = ws_mse[0] / 8388608.0f;
    out[OUT_LOSS] = mse + 0.25f * mse;
  }
}

extern "C" void kernel_launch(void* const* d_in, const int* in_sizes, int n_in,
                              void* d_out, int out_size, void* d_ws, size_t ws_size,
                              hipStream_t stream) {
  (void)in_sizes; (void)n_in; (void)out_size; (void)ws_size;
  const float* xin = (const float*)d_in[0];
  const float* cb  = (const float*)d_in[1];
  float* out = (float*)d_out;

  char* wsb = (char*)d_ws;
  float* ws_mse = (float*)wsb;                              // [0,4)
  unsigned int* ws_hist = (unsigned int*)(wsb + 4);         // [4,4100)
  float* ws_ee = (float*)(wsb + 4352);                      // [4352,8448)
  unsigned short* ws_cbh = (unsigned short*)(wsb + 8448);   // [8448,139520)
  unsigned short* ws_cbl = (unsigned short*)(wsb + 139520); // [139520,270592)

  hipMemsetAsync(d_ws, 0, 4100, stream);
  hipLaunchKernelGGL(vq_prep_kernel, dim3(4), dim3(256), 0, stream,
                     cb, ws_cbh, ws_cbl, ws_ee);
  hipLaunchKernelGGL(vq_mfma_kernel, dim3(NTOK / 64), dim3(256), 0, stream,
                     xin, ws_cbh, ws_cbl, ws_ee, out);
  hipLaunchKernelGGL(vq_exact_kernel, dim3(256), dim3(256), 0, stream,
                     xin, cb, ws_ee, out);
  hipLaunchKernelGGL(vq_epilogue_kernel, dim3(NTOK / 256), dim3(256), 0, stream,
                     xin, cb, out, ws_mse, ws_hist);
  hipLaunchKernelGGL(vq_final_kernel, dim3(1), dim3(1024), 0, stream,
                     ws_hist, ws_mse, out);
}